// Round 10
// baseline (227.137 us; speedup 1.0000x reference)
//
#include <hip/hip_runtime.h>
#include <hip/hip_bf16.h>
#include <string.h>

typedef unsigned short ushort_t;
typedef __attribute__((ext_vector_type(8))) short short8;      // 8 x bf16 (4 VGPRs)
typedef __attribute__((ext_vector_type(4))) short short4v;     // 4 x bf16 (2 VGPRs)
typedef __attribute__((ext_vector_type(4))) float floatx4;     // MFMA accum / fp32 vec load
typedef __attribute__((ext_vector_type(4))) int int4v;         // 16B vector ld/st
typedef __attribute__((ext_vector_type(4))) unsigned short us4; // 8B bf16 vector

#define MFMA(a, b, c) __builtin_amdgcn_mfma_f32_16x16x32_bf16(a, b, c, 0, 0, 0)
#define MFMA16(a, b, c) __builtin_amdgcn_mfma_f32_16x16x16bf16_1k(a, b, c, 0, 0, 0)

__device__ __forceinline__ float b2f(ushort_t u) {
    union { float f; unsigned i; } c; c.i = ((unsigned)u) << 16; return c.f;
}
__device__ __forceinline__ ushort_t f2b(float f) {
    union { float f; unsigned i; } c; c.f = f;
    unsigned r = c.i + 0x7FFFu + ((c.i >> 16) & 1u);
    return (ushort_t)(r >> 16);
}
// packed f32x2 -> bf16x2 (v_cvt_pk_bf16_f32 on gfx950)
__device__ __forceinline__ unsigned pk_bf16(float a, float b) {
    float2 f; f.x = a; f.y = b;
    __hip_bfloat162 h = __float22bfloat162_rn(f);
    unsigned u;
    memcpy(&u, &h, 4);   // folded to a register alias at -O3
    return u;
}
// async global->LDS DMA, 16B per lane; ldst must be wave-uniform
__device__ __forceinline__ void gl_lds16(const ushort_t* g, ushort_t* l) {
    __builtin_amdgcn_global_load_lds(
        (const __attribute__((address_space(1))) void*)g,
        (__attribute__((address_space(3))) void*)l, 16, 0, 0);
}

// ---------------------------------------------------------------------------
// RMSNorm: x fp32 [4096][1024] -> xn bf16; xn = x / max(||x||,eps) * 32 * (1+gamma)
// ---------------------------------------------------------------------------
__global__ __launch_bounds__(256) void rmsnorm_k(const float* __restrict__ x,
                                                 const float* __restrict__ gamma,
                                                 ushort_t* __restrict__ xn) {
    int row = blockIdx.x;
    const float* xr = x + (size_t)row * 1024;
    ushort_t* orow = xn + (size_t)row * 1024;
    int t = threadIdx.x;

    floatx4 u = *(const floatx4*)&xr[t * 4];
    float ss = u[0] * u[0] + u[1] * u[1] + u[2] * u[2] + u[3] * u[3];
    #pragma unroll
    for (int off = 32; off; off >>= 1) ss += __shfl_xor(ss, off);
    __shared__ float red[4];
    if ((t & 63) == 0) red[t >> 6] = ss;
    __syncthreads();
    float tot = red[0] + red[1] + red[2] + red[3];
    float inv = rsqrtf(fmaxf(tot, 1e-24f)) * 32.0f;

    floatx4 g = *(const floatx4*)&gamma[t * 4];
    us4 o;
    o.x = f2b(u[0] * inv * (1.0f + g[0]));
    o.y = f2b(u[1] * inv * (1.0f + g[1]));
    o.z = f2b(u[2] * inv * (1.0f + g[2]));
    o.w = f2b(u[3] * inv * (1.0f + g[3]));
    *(us4*)&orow[t * 4] = o;
}

// ---------------------------------------------------------------------------
// Transpose+convert both weights in one dispatch: fp32 [K][N] -> bf16 [N][K].
// blocks 0..767: w_qkv (1024x3072); 768..1023: w_out (1024x1024).
// ---------------------------------------------------------------------------
__global__ __launch_bounds__(256) void transpose_cvt2_k(const float* __restrict__ wq,
                                                        ushort_t* __restrict__ oq,
                                                        const float* __restrict__ wo,
                                                        ushort_t* __restrict__ oo) {
    __shared__ ushort_t Ts[64 * 72];
    int bid = blockIdx.x;
    const float* in; ushort_t* out; int K, N, n0, k0;
    if (bid < 768) { in = wq; out = oq; K = 1024; N = 3072;
                     n0 = (bid % 48) * 64; k0 = (bid / 48) * 64; }
    else           { int b2 = bid - 768; in = wo; out = oo; K = 1024; N = 1024;
                     n0 = (b2 & 15) * 64; k0 = (b2 >> 4) * 64; }
    int t = threadIdx.x;
    #pragma unroll
    for (int i = 0; i < 4; i++) {
        int idx = t + i * 256;              // 0..1023
        int r = idx >> 4, g = idx & 15;     // r = k-row, g = 4-col group
        floatx4 v = *(const floatx4*)&in[(size_t)(k0 + r) * N + n0 + g * 4];
        us4 o; o.x = f2b(v[0]); o.y = f2b(v[1]); o.z = f2b(v[2]); o.w = f2b(v[3]);
        *(us4*)&Ts[r * 72 + g * 4] = o;
    }
    __syncthreads();
    #pragma unroll
    for (int i = 0; i < 2; i++) {
        int idx = t + i * 256;
        int r = idx >> 3, g = idx & 7;      // r = local n, g = k-group
        ushort_t tmp[8];
        #pragma unroll
        for (int j = 0; j < 8; j++) tmp[j] = Ts[(g * 8 + j) * 72 + r];
        *(int4v*)&out[(size_t)(n0 + r) * K + k0 + g * 8] = *(const int4v*)tmp;
    }
}

// ---------------------------------------------------------------------------
// Transpose bf16 [4096 tok][3072] V-columns (2048..3071) -> vT [1024 ch][4096 tok]
// ---------------------------------------------------------------------------
__global__ __launch_bounds__(256) void transpose_v_k(const ushort_t* __restrict__ qkv,
                                                     ushort_t* __restrict__ vT) {
    __shared__ ushort_t Ts[64 * 72];
    int t = threadIdx.x;
    int t0 = blockIdx.x * 64;           // token tile
    int c0 = blockIdx.y * 64;           // channel tile
    const ushort_t* in = qkv + 2048 + c0;
    #pragma unroll
    for (int i = 0; i < 2; i++) {
        int idx = t + i * 256;
        int r = idx >> 3, g = idx & 7;  // r = token row, g = 8-ch group
        *(int4v*)&Ts[r * 72 + g * 8] =
            *(const int4v*)&in[(size_t)(t0 + r) * 3072 + g * 8];
    }
    __syncthreads();
    #pragma unroll
    for (int i = 0; i < 2; i++) {
        int idx = t + i * 256;
        int r = idx >> 3, g = idx & 7;  // r = local ch, g = token group
        ushort_t tmp[8];
        #pragma unroll
        for (int j = 0; j < 8; j++) tmp[j] = Ts[(g * 8 + j) * 72 + r];
        *(int4v*)&vT[(size_t)(c0 + r) * 4096 + t0 + g * 8] = *(const int4v*)tmp;
    }
}

// ---------------------------------------------------------------------------
// GEMM, m97-style: C[M][N] = A[M][K] * Bt[N][K]^T  (A,Bt bf16; C bf16 or fp32)
// 128x128 tile, 4 waves. BK=64, unpadded 128x64 LDS tiles staged via
// global_load_lds (16B/lane DMA) with XOR chunk-swizzle.
// ---------------------------------------------------------------------------
template <bool F32OUT>
__global__ __launch_bounds__(256) void gemm_tn(const ushort_t* __restrict__ A,
                                               const ushort_t* __restrict__ Bt,
                                               void* __restrict__ Cv,
                                               int M, int N, int K) {
    __shared__ ushort_t As[128 * 64];
    __shared__ ushort_t Bs[128 * 64];
    int t = threadIdx.x;
    int m0 = blockIdx.y * 128, n0 = blockIdx.x * 128;
    int lane = t & 63, wave = t >> 6, quad = lane >> 4, l16 = lane & 15;
    int wm = (wave & 1) * 64, wn = (wave >> 1) * 64;
    floatx4 acc[4][4] = {};

    int srow = lane >> 3;                 // relative row 0..7
    int schunk = (lane & 7) ^ srow;       // swizzled global 16B-chunk
    const ushort_t* Ag = A + (size_t)(m0 + wave * 8 + srow) * K + schunk * 8;
    const ushort_t* Bg = Bt + (size_t)(n0 + wave * 8 + srow) * K + schunk * 8;
    int lbase = (wave * 8) * 64;
    int xq = l16 & 7;                     // read-side swizzle key

    for (int k1 = 0; k1 < K; k1 += 64) {
        #pragma unroll
        for (int i = 0; i < 4; i++) {
            gl_lds16(Ag + (size_t)(i * 32) * K + k1, &As[lbase + i * 32 * 64]);
            gl_lds16(Bg + (size_t)(i * 32) * K + k1, &Bs[lbase + i * 32 * 64]);
        }
        __syncthreads();
        #pragma unroll
        for (int ks = 0; ks < 2; ks++) {
            int ca = ((ks * 4 + quad) ^ xq) * 8;
            short8 af[4], bf[4];
            #pragma unroll
            for (int i = 0; i < 4; i++) {
                af[i] = *(const short8*)&As[(wm + i * 16 + l16) * 64 + ca];
                bf[i] = *(const short8*)&Bs[(wn + i * 16 + l16) * 64 + ca];
            }
            #pragma unroll
            for (int mt = 0; mt < 4; mt++)
                #pragma unroll
                for (int nt = 0; nt < 4; nt++)
                    acc[mt][nt] = MFMA(af[mt], bf[nt], acc[mt][nt]);
        }
        __syncthreads();
    }
    #pragma unroll
    for (int mt = 0; mt < 4; mt++)
        #pragma unroll
        for (int r = 0; r < 4; r++) {
            int row = m0 + wm + mt * 16 + quad * 4 + r;
            #pragma unroll
            for (int nt = 0; nt < 4; nt++) {
                int col = n0 + wn + nt * 16 + l16;
                if constexpr (F32OUT)
                    ((float*)Cv)[(size_t)row * N + col] = acc[mt][nt][r];
                else
                    ((ushort_t*)Cv)[(size_t)row * N + col] = f2b(acc[mt][nt][r]);
            }
        }
}

// ---------------------------------------------------------------------------
// Flash attention, wave-level kseq-split (8 waves: 0-3 kseq[0,1024),
// 4-7 kseq[1024,2048), same 128 q-rows). No-max softmax => partials are
// additive; combine O/denom through LDS, epilogue by lower waves.
// Per half: LDS K/V staging (shared by 4 waves) + register prefetch dbuf.
// P in registers: S^T = K*Q^T (x32) -> C-layout = x16 A-layout -> exp2 ->
// packed bf16 -> PV + ones-rowsum via MFMA16.
// qkv bf16 [4096][3072] (Q|K|V), vT bf16 [1024 ch][4096 tok], o bf16 [4096][1024]
// Grid 512 = 16 qb x 32 bh (bid&31=bh pins head to XCD bid%8); 512 thr.
// ---------------------------------------------------------------------------
#define LDA 72
__global__ __launch_bounds__(512, 4) void attn_k(const ushort_t* __restrict__ qkv,
                                                 const ushort_t* __restrict__ vT,
                                                 ushort_t* __restrict__ o) {
    __shared__ ushort_t S[4][64 * LDA];   // K0, V0, K1, V1
    int t = threadIdx.x;
    int lane = t & 63, wave = t >> 6, quad = lane >> 4, l16 = lane & 15;
    int half = wave >> 2, w4 = wave & 3;
    int bid = blockIdx.x;
    int bh = bid & 31, qb = bid >> 5;
    int b = bh >> 4, h = bh & 15;
    int q0 = qb * 128 + w4 * 32;
    const size_t RS = 3072;
    const ushort_t* Qb = qkv + (size_t)b * 2048 * RS + h * 64;
    const ushort_t* Kb = Qb + 1024;
    const ushort_t* Vb = vT + (size_t)(h * 64) * 4096 + b * 2048;
    const float SC = 0.18033688011112042f;  // (1/8) * log2(e)

    ushort_t* Ks = S[half * 2];
    ushort_t* Vt = S[half * 2 + 1];

    // staging: 256 threads of this half cover the 64x64 K and V tiles
    int ht = t & 255;
    int srow = ht >> 2, sseg = ht & 3;
    int kbase = half * 1024;
    const ushort_t* Kg = Kb + (size_t)(kbase + srow) * RS + sseg * 8;
    const ushort_t* Vg = Vb + (size_t)srow * 4096 + kbase + sseg * 8;

    // Q B-frags (n=q=l16, k=d=quad*8+j), pre-scaled by SC
    short8 qf[2][2];
    #pragma unroll
    for (int qt = 0; qt < 2; qt++)
        #pragma unroll
        for (int ks = 0; ks < 2; ks++) {
            union { short8 s; ushort_t u[8]; } a;
            a.s = *(const short8*)&Qb[(size_t)(q0 + qt * 16 + l16) * RS + ks * 32 + quad * 8];
            #pragma unroll
            for (int j = 0; j < 8; j++) a.u[j] = f2b(b2f(a.u[j]) * SC);
            qf[qt][ks] = a.s;
        }

    short4v ones4;
    #pragma unroll
    for (int j = 0; j < 4; j++) ones4[j] = (short)0x3F80;  // bf16 1.0

    floatx4 oacc[2][4] = {};
    floatx4 sum_acc[2] = {};

    // prefetch this half's tile 0
    int4v kr0 = *(const int4v*)Kg;
    int4v kr1 = *(const int4v*)(Kg + 32);
    int4v vr0 = *(const int4v*)Vg;
    int4v vr1 = *(const int4v*)(Vg + 32);

    for (int kt = 0; kt < 1024; kt += 64) {
        __syncthreads();
        *(int4v*)&Ks[srow * LDA + sseg * 8] = kr0;
        *(int4v*)&Ks[srow * LDA + 32 + sseg * 8] = kr1;
        *(int4v*)&Vt[srow * LDA + sseg * 8] = vr0;
        *(int4v*)&Vt[srow * LDA + 32 + sseg * 8] = vr1;
        __syncthreads();

        if (kt + 64 < 1024) {   // prefetch next tile; consumed next iter
            const ushort_t* Kg2 = Kg + (size_t)(kt + 64) * RS;
            const ushort_t* Vg2 = Vg + (kt + 64);
            kr0 = *(const int4v*)Kg2;
            kr1 = *(const int4v*)(Kg2 + 32);
            vr0 = *(const int4v*)Vg2;
            vr1 = *(const int4v*)(Vg2 + 32);
        }

        // S^T[kseq][q]: A = K-frag (m=kseq), B = Q-frag (n=q)
        floatx4 s[2][4];
        #pragma unroll
        for (int mt = 0; mt < 4; mt++) {
            short8 kf0 = *(const short8*)&Ks[(mt * 16 + l16) * LDA + quad * 8];
            short8 kf1 = *(const short8*)&Ks[(mt * 16 + l16) * LDA + 32 + quad * 8];
            #pragma unroll
            for (int qt = 0; qt < 2; qt++) {
                floatx4 z = {};
                z = MFMA(kf0, qf[qt][0], z);
                s[qt][mt] = MFMA(kf1, qf[qt][1], z);
            }
        }

        // P = exp2(S) packed as x16 A-frags (m=q=l16, k=kseq=quad*4+j)
        short4v pa[2][4];
        #pragma unroll
        for (int qt = 0; qt < 2; qt++)
            #pragma unroll
            for (int mt = 0; mt < 4; mt++) {
                union { short4v v; unsigned u[2]; } pk;
                pk.u[0] = pk_bf16(exp2f(s[qt][mt][0]), exp2f(s[qt][mt][1]));
                pk.u[1] = pk_bf16(exp2f(s[qt][mt][2]), exp2f(s[qt][mt][3]));
                pa[qt][mt] = pk.v;
            }

        // O += P V ; denom += P @ ones
        #pragma unroll
        for (int mt = 0; mt < 4; mt++) {
            short4v vb[4];
            #pragma unroll
            for (int dt = 0; dt < 4; dt++)
                vb[dt] = *(const short4v*)&Vt[(dt * 16 + l16) * LDA + mt * 16 + quad * 4];
            #pragma unroll
            for (int qt = 0; qt < 2; qt++) {
                sum_acc[qt] = MFMA16(pa[qt][mt], ones4, sum_acc[qt]);
                #pragma unroll
                for (int dt = 0; dt < 4; dt++)
                    oacc[qt][dt] = MFMA16(pa[qt][mt], vb[dt], oacc[qt][dt]);
            }
        }
    }

    // combine halves through LDS (2 phases of 20 KB; all-dead staging reused)
    float* xb = (float*)&S[0][0];
    int ci = (w4 * 64 + lane) * 20;
    #pragma unroll
    for (int qt = 0; qt < 2; qt++) {
        __syncthreads();
        if (half == 1) {
            #pragma unroll
            for (int dt = 0; dt < 4; dt++)
                #pragma unroll
                for (int r = 0; r < 4; r++) xb[ci + dt * 4 + r] = oacc[qt][dt][r];
            #pragma unroll
            for (int r = 0; r < 4; r++) xb[ci + 16 + r] = sum_acc[qt][r];
        }
        __syncthreads();
        if (half == 0) {
            #pragma unroll
            for (int dt = 0; dt < 4; dt++)
                #pragma unroll
                for (int r = 0; r < 4; r++) oacc[qt][dt][r] += xb[ci + dt * 4 + r];
            #pragma unroll
            for (int r = 0; r < 4; r++) sum_acc[qt][r] += xb[ci + 16 + r];
        }
    }

    if (half == 0) {
        ushort_t* ob = o + (size_t)b * 2048 * 1024 + h * 64;
        #pragma unroll
        for (int qt = 0; qt < 2; qt++)
            #pragma unroll
            for (int r = 0; r < 4; r++) {
                float inv = 1.0f / sum_acc[qt][r];
                int row = q0 + qt * 16 + quad * 4 + r;
                #pragma unroll
                for (int dt = 0; dt < 4; dt++)
                    ob[(size_t)row * 1024 + dt * 16 + l16] = f2b(oacc[qt][dt][r] * inv);
            }
    }
}

// ---------------------------------------------------------------------------
extern "C" void kernel_launch(void* const* d_in, const int* in_sizes, int n_in,
                              void* d_out, int out_size, void* d_ws, size_t ws_size,
                              hipStream_t stream) {
    const float* x     = (const float*)d_in[0];   // [2,2048,1024] fp32
    const float* gamma = (const float*)d_in[1];   // [1024] fp32
    const float* w_qkv = (const float*)d_in[2];   // [1024][3072] fp32
    const float* w_out = (const float*)d_in[3];   // [1024][1024] fp32
    float* out = (float*)d_out;                   // [4096][1024] fp32

    ushort_t* ws   = (ushort_t*)d_ws;
    ushort_t* xn   = ws;                                  // 4096*1024 (8MB, reused as attn)
    ushort_t* qkv  = xn + (size_t)4096 * 1024;            // 4096*3072 (24MB) Q|K|V
    ushort_t* vTb  = qkv + (size_t)4096 * 3072;           // 1024*4096 (8MB)  V^T
    ushort_t* wtq  = vTb + (size_t)1024 * 4096;           // 3072*1024 (6MB)
    ushort_t* wto  = wtq + (size_t)3072 * 1024;           // 1024*1024 (2MB)
    ushort_t* attn = xn;  // xn dead after QKV gemm inputs consumed

    rmsnorm_k<<<4096, 256, 0, stream>>>(x, gamma, xn);
    transpose_cvt2_k<<<1024, 256, 0, stream>>>(w_qkv, wtq, w_out, wto);
    // QKV: [4096 tok][3072 ch], 768 blocks = 3/CU
    gemm_tn<false><<<dim3(24, 32), 256, 0, stream>>>(xn, wtq, qkv, 4096, 3072, 1024);
    // V^T: [1024 ch][4096 tok] via bf16 transpose of V columns (L2-resident)
    transpose_v_k<<<dim3(64, 16), 256, 0, stream>>>(qkv, vTb);
    attn_k<<<512, 512, 0, stream>>>(qkv, vTb, attn);
    gemm_tn<true><<<dim3(8, 32), 256, 0, stream>>>(attn, wto, out, 4096, 1024, 1024);
}

// Round 11
// 194.003 us; speedup vs baseline: 1.1708x; 1.1708x over previous
//
#include <hip/hip_runtime.h>
#include <hip/hip_bf16.h>
#include <string.h>

typedef unsigned short ushort_t;
typedef __attribute__((ext_vector_type(8))) short short8;      // 8 x bf16 (4 VGPRs)
typedef __attribute__((ext_vector_type(4))) short short4v;     // 4 x bf16 (2 VGPRs)
typedef __attribute__((ext_vector_type(4))) float floatx4;     // MFMA accum / fp32 vec load
typedef __attribute__((ext_vector_type(4))) int int4v;         // 16B vector ld/st
typedef __attribute__((ext_vector_type(4))) unsigned short us4; // 8B bf16 vector

#define MFMA(a, b, c) __builtin_amdgcn_mfma_f32_16x16x32_bf16(a, b, c, 0, 0, 0)
#define MFMA16(a, b, c) __builtin_amdgcn_mfma_f32_16x16x16bf16_1k(a, b, c, 0, 0, 0)
#define EXP2(x) __builtin_amdgcn_exp2f(x)   // raw v_exp_f32, no libm fixup

__device__ __forceinline__ float b2f(ushort_t u) {
    union { float f; unsigned i; } c; c.i = ((unsigned)u) << 16; return c.f;
}
__device__ __forceinline__ ushort_t f2b(float f) {
    union { float f; unsigned i; } c; c.f = f;
    unsigned r = c.i + 0x7FFFu + ((c.i >> 16) & 1u);
    return (ushort_t)(r >> 16);
}
// packed f32x2 -> bf16x2 (v_cvt_pk_bf16_f32 on gfx950)
__device__ __forceinline__ unsigned pk_bf16(float a, float b) {
    float2 f; f.x = a; f.y = b;
    __hip_bfloat162 h = __float22bfloat162_rn(f);
    unsigned u;
    memcpy(&u, &h, 4);   // folded to a register alias at -O3
    return u;
}
// async global->LDS DMA, 16B per lane; ldst must be wave-uniform
__device__ __forceinline__ void gl_lds16(const ushort_t* g, ushort_t* l) {
    __builtin_amdgcn_global_load_lds(
        (const __attribute__((address_space(1))) void*)g,
        (__attribute__((address_space(3))) void*)l, 16, 0, 0);
}

// ---------------------------------------------------------------------------
// RMSNorm: x fp32 [4096][1024] -> xn bf16; xn = x / max(||x||,eps) * 32 * (1+gamma)
// ---------------------------------------------------------------------------
__global__ __launch_bounds__(256) void rmsnorm_k(const float* __restrict__ x,
                                                 const float* __restrict__ gamma,
                                                 ushort_t* __restrict__ xn) {
    int row = blockIdx.x;
    const float* xr = x + (size_t)row * 1024;
    ushort_t* orow = xn + (size_t)row * 1024;
    int t = threadIdx.x;

    floatx4 u = *(const floatx4*)&xr[t * 4];
    float ss = u[0] * u[0] + u[1] * u[1] + u[2] * u[2] + u[3] * u[3];
    #pragma unroll
    for (int off = 32; off; off >>= 1) ss += __shfl_xor(ss, off);
    __shared__ float red[4];
    if ((t & 63) == 0) red[t >> 6] = ss;
    __syncthreads();
    float tot = red[0] + red[1] + red[2] + red[3];
    float inv = rsqrtf(fmaxf(tot, 1e-24f)) * 32.0f;

    floatx4 g = *(const floatx4*)&gamma[t * 4];
    us4 o;
    o.x = f2b(u[0] * inv * (1.0f + g[0]));
    o.y = f2b(u[1] * inv * (1.0f + g[1]));
    o.z = f2b(u[2] * inv * (1.0f + g[2]));
    o.w = f2b(u[3] * inv * (1.0f + g[3]));
    *(us4*)&orow[t * 4] = o;
}

// ---------------------------------------------------------------------------
// Transpose+convert both weights in one dispatch: fp32 [K][N] -> bf16 [N][K].
// blocks 0..767: w_qkv (1024x3072); 768..1023: w_out (1024x1024).
// ---------------------------------------------------------------------------
__global__ __launch_bounds__(256) void transpose_cvt2_k(const float* __restrict__ wq,
                                                        ushort_t* __restrict__ oq,
                                                        const float* __restrict__ wo,
                                                        ushort_t* __restrict__ oo) {
    __shared__ ushort_t Ts[64 * 72];
    int bid = blockIdx.x;
    const float* in; ushort_t* out; int K, N, n0, k0;
    if (bid < 768) { in = wq; out = oq; K = 1024; N = 3072;
                     n0 = (bid % 48) * 64; k0 = (bid / 48) * 64; }
    else           { int b2 = bid - 768; in = wo; out = oo; K = 1024; N = 1024;
                     n0 = (b2 & 15) * 64; k0 = (b2 >> 4) * 64; }
    int t = threadIdx.x;
    #pragma unroll
    for (int i = 0; i < 4; i++) {
        int idx = t + i * 256;              // 0..1023
        int r = idx >> 4, g = idx & 15;     // r = k-row, g = 4-col group
        floatx4 v = *(const floatx4*)&in[(size_t)(k0 + r) * N + n0 + g * 4];
        us4 o; o.x = f2b(v[0]); o.y = f2b(v[1]); o.z = f2b(v[2]); o.w = f2b(v[3]);
        *(us4*)&Ts[r * 72 + g * 4] = o;
    }
    __syncthreads();
    #pragma unroll
    for (int i = 0; i < 2; i++) {
        int idx = t + i * 256;
        int r = idx >> 3, g = idx & 7;      // r = local n, g = k-group
        ushort_t tmp[8];
        #pragma unroll
        for (int j = 0; j < 8; j++) tmp[j] = Ts[(g * 8 + j) * 72 + r];
        *(int4v*)&out[(size_t)(n0 + r) * K + k0 + g * 8] = *(const int4v*)tmp;
    }
}

// ---------------------------------------------------------------------------
// Transpose bf16 [4096 tok][3072] V-columns (2048..3071) -> vT [1024 ch][4096 tok]
// ---------------------------------------------------------------------------
__global__ __launch_bounds__(256) void transpose_v_k(const ushort_t* __restrict__ qkv,
                                                     ushort_t* __restrict__ vT) {
    __shared__ ushort_t Ts[64 * 72];
    int t = threadIdx.x;
    int t0 = blockIdx.x * 64;           // token tile
    int c0 = blockIdx.y * 64;           // channel tile
    const ushort_t* in = qkv + 2048 + c0;
    #pragma unroll
    for (int i = 0; i < 2; i++) {
        int idx = t + i * 256;
        int r = idx >> 3, g = idx & 7;  // r = token row, g = 8-ch group
        *(int4v*)&Ts[r * 72 + g * 8] =
            *(const int4v*)&in[(size_t)(t0 + r) * 3072 + g * 8];
    }
    __syncthreads();
    #pragma unroll
    for (int i = 0; i < 2; i++) {
        int idx = t + i * 256;
        int r = idx >> 3, g = idx & 7;  // r = local ch, g = token group
        ushort_t tmp[8];
        #pragma unroll
        for (int j = 0; j < 8; j++) tmp[j] = Ts[(g * 8 + j) * 72 + r];
        *(int4v*)&vT[(size_t)(c0 + r) * 4096 + t0 + g * 8] = *(const int4v*)tmp;
    }
}

// ---------------------------------------------------------------------------
// GEMM, m97-style: C[M][N] = A[M][K] * Bt[N][K]^T  (A,Bt bf16; C bf16 or fp32)
// 128x128 tile, 4 waves. BK=64, unpadded 128x64 LDS tiles staged via
// global_load_lds (16B/lane DMA) with XOR chunk-swizzle.
// ---------------------------------------------------------------------------
template <bool F32OUT>
__global__ __launch_bounds__(256) void gemm_tn(const ushort_t* __restrict__ A,
                                               const ushort_t* __restrict__ Bt,
                                               void* __restrict__ Cv,
                                               int M, int N, int K) {
    __shared__ ushort_t As[128 * 64];
    __shared__ ushort_t Bs[128 * 64];
    int t = threadIdx.x;
    int m0 = blockIdx.y * 128, n0 = blockIdx.x * 128;
    int lane = t & 63, wave = t >> 6, quad = lane >> 4, l16 = lane & 15;
    int wm = (wave & 1) * 64, wn = (wave >> 1) * 64;
    floatx4 acc[4][4] = {};

    int srow = lane >> 3;                 // relative row 0..7
    int schunk = (lane & 7) ^ srow;       // swizzled global 16B-chunk
    const ushort_t* Ag = A + (size_t)(m0 + wave * 8 + srow) * K + schunk * 8;
    const ushort_t* Bg = Bt + (size_t)(n0 + wave * 8 + srow) * K + schunk * 8;
    int lbase = (wave * 8) * 64;
    int xq = l16 & 7;                     // read-side swizzle key

    for (int k1 = 0; k1 < K; k1 += 64) {
        #pragma unroll
        for (int i = 0; i < 4; i++) {
            gl_lds16(Ag + (size_t)(i * 32) * K + k1, &As[lbase + i * 32 * 64]);
            gl_lds16(Bg + (size_t)(i * 32) * K + k1, &Bs[lbase + i * 32 * 64]);
        }
        __syncthreads();
        #pragma unroll
        for (int ks = 0; ks < 2; ks++) {
            int ca = ((ks * 4 + quad) ^ xq) * 8;
            short8 af[4], bf[4];
            #pragma unroll
            for (int i = 0; i < 4; i++) {
                af[i] = *(const short8*)&As[(wm + i * 16 + l16) * 64 + ca];
                bf[i] = *(const short8*)&Bs[(wn + i * 16 + l16) * 64 + ca];
            }
            #pragma unroll
            for (int mt = 0; mt < 4; mt++)
                #pragma unroll
                for (int nt = 0; nt < 4; nt++)
                    acc[mt][nt] = MFMA(af[mt], bf[nt], acc[mt][nt]);
        }
        __syncthreads();
    }
    #pragma unroll
    for (int mt = 0; mt < 4; mt++)
        #pragma unroll
        for (int r = 0; r < 4; r++) {
            int row = m0 + wm + mt * 16 + quad * 4 + r;
            #pragma unroll
            for (int nt = 0; nt < 4; nt++) {
                int col = n0 + wn + nt * 16 + l16;
                if constexpr (F32OUT)
                    ((float*)Cv)[(size_t)row * N + col] = acc[mt][nt][r];
                else
                    ((ushort_t*)Cv)[(size_t)row * N + col] = f2b(acc[mt][nt][r]);
            }
        }
}

// ---------------------------------------------------------------------------
// Flash attention (round-9 structure + raw v_exp_f32):
//   LDS K/V staging (shared by 4 waves) + register prefetch double-buffer.
//   P in registers: S^T = K*Q^T (x32) -> C-layout = x16 A-layout -> exp2 ->
//   packed bf16 -> PV + ones-rowsum via MFMA16. No cross-lane ops.
// qkv bf16 [4096][3072] (Q|K|V), vT bf16 [1024 ch][4096 tok], o bf16 [4096][1024]
// Grid 512 = 16 qb x 32 bh (bid&31=bh pins head to XCD bid%8); 256 thr.
// ---------------------------------------------------------------------------
#define LDA 72
__global__ __launch_bounds__(256, 2) void attn_k(const ushort_t* __restrict__ qkv,
                                                 const ushort_t* __restrict__ vT,
                                                 ushort_t* __restrict__ o) {
    __shared__ ushort_t Ks[64 * LDA];   // [kseq_local][d]
    __shared__ ushort_t Vt[64 * LDA];   // [d][kseq_local]
    int t = threadIdx.x;
    int lane = t & 63, wave = t >> 6, quad = lane >> 4, l16 = lane & 15;
    int bid = blockIdx.x;
    int bh = bid & 31, qb = bid >> 5;
    int b = bh >> 4, h = bh & 15;
    int q0 = qb * 128 + wave * 32;
    const size_t RS = 3072;
    const ushort_t* Qb = qkv + (size_t)b * 2048 * RS + h * 64;
    const ushort_t* Kb = Qb + 1024;
    const ushort_t* Vb = vT + (size_t)(h * 64) * 4096 + b * 2048;
    const float SC = 0.18033688011112042f;  // (1/8) * log2(e)

    // staging indices: 4 threads per row, 2 b128 each
    int srow = t >> 2, sseg = t & 3;
    const ushort_t* Kg = Kb + (size_t)srow * RS + sseg * 8;
    const ushort_t* Vg = Vb + (size_t)srow * 4096 + sseg * 8;

    // Q B-frags (n=q=l16, k=d=quad*8+j), pre-scaled by SC
    short8 qf[2][2];
    #pragma unroll
    for (int qt = 0; qt < 2; qt++)
        #pragma unroll
        for (int ks = 0; ks < 2; ks++) {
            union { short8 s; ushort_t u[8]; } a;
            a.s = *(const short8*)&Qb[(size_t)(q0 + qt * 16 + l16) * RS + ks * 32 + quad * 8];
            #pragma unroll
            for (int j = 0; j < 8; j++) a.u[j] = f2b(b2f(a.u[j]) * SC);
            qf[qt][ks] = a.s;
        }

    short4v ones4;
    #pragma unroll
    for (int j = 0; j < 4; j++) ones4[j] = (short)0x3F80;  // bf16 1.0

    floatx4 oacc[2][4] = {};
    floatx4 sum_acc[2] = {};

    // prefetch tile 0 into registers
    int4v kr0 = *(const int4v*)Kg;
    int4v kr1 = *(const int4v*)(Kg + 32);
    int4v vr0 = *(const int4v*)Vg;
    int4v vr1 = *(const int4v*)(Vg + 32);

    for (int kt = 0; kt < 2048; kt += 64) {
        __syncthreads();   // previous tile's readers done
        *(int4v*)&Ks[srow * LDA + sseg * 8] = kr0;
        *(int4v*)&Ks[srow * LDA + 32 + sseg * 8] = kr1;
        *(int4v*)&Vt[srow * LDA + sseg * 8] = vr0;
        *(int4v*)&Vt[srow * LDA + 32 + sseg * 8] = vr1;
        __syncthreads();   // tile visible to all waves

        if (kt + 64 < 2048) {   // issue next tile's loads now; consumed next iter
            const ushort_t* Kg2 = Kg + (size_t)(kt + 64) * RS;
            const ushort_t* Vg2 = Vg + (kt + 64);
            kr0 = *(const int4v*)Kg2;
            kr1 = *(const int4v*)(Kg2 + 32);
            vr0 = *(const int4v*)Vg2;
            vr1 = *(const int4v*)(Vg2 + 32);
        }

        // S^T[kseq][q]: A = K-frag (m=kseq), B = Q-frag (n=q)
        floatx4 s[2][4];
        #pragma unroll
        for (int mt = 0; mt < 4; mt++) {
            short8 kf0 = *(const short8*)&Ks[(mt * 16 + l16) * LDA + quad * 8];
            short8 kf1 = *(const short8*)&Ks[(mt * 16 + l16) * LDA + 32 + quad * 8];
            #pragma unroll
            for (int qt = 0; qt < 2; qt++) {
                floatx4 z = {};
                z = MFMA(kf0, qf[qt][0], z);
                s[qt][mt] = MFMA(kf1, qf[qt][1], z);
            }
        }

        // P = exp2(S) packed as x16 A-frags (m=q=l16, k=kseq=quad*4+j)
        short4v pa[2][4];
        #pragma unroll
        for (int qt = 0; qt < 2; qt++)
            #pragma unroll
            for (int mt = 0; mt < 4; mt++) {
                union { short4v v; unsigned u[2]; } pk;
                pk.u[0] = pk_bf16(EXP2(s[qt][mt][0]), EXP2(s[qt][mt][1]));
                pk.u[1] = pk_bf16(EXP2(s[qt][mt][2]), EXP2(s[qt][mt][3]));
                pa[qt][mt] = pk.v;
            }

        // O += P V ; denom += P @ ones  (V B-frags from Vt: n=d=l16, k=kseq)
        #pragma unroll
        for (int mt = 0; mt < 4; mt++) {
            short4v vb[4];
            #pragma unroll
            for (int dt = 0; dt < 4; dt++)
                vb[dt] = *(const short4v*)&Vt[(dt * 16 + l16) * LDA + mt * 16 + quad * 4];
            #pragma unroll
            for (int qt = 0; qt < 2; qt++) {
                sum_acc[qt] = MFMA16(pa[qt][mt], ones4, sum_acc[qt]);
                #pragma unroll
                for (int dt = 0; dt < 4; dt++)
                    oacc[qt][dt] = MFMA16(pa[qt][mt], vb[dt], oacc[qt][dt]);
            }
        }
    }

    // epilogue: rows q = q0+qt*16+quad*4+r, cols d = dt*16+l16
    ushort_t* ob = o + (size_t)b * 2048 * 1024 + h * 64;
    #pragma unroll
    for (int qt = 0; qt < 2; qt++)
        #pragma unroll
        for (int r = 0; r < 4; r++) {
            float inv = 1.0f / sum_acc[qt][r];
            int row = q0 + qt * 16 + quad * 4 + r;
            #pragma unroll
            for (int dt = 0; dt < 4; dt++)
                ob[(size_t)row * 1024 + dt * 16 + l16] = f2b(oacc[qt][dt][r] * inv);
        }
}

// ---------------------------------------------------------------------------
extern "C" void kernel_launch(void* const* d_in, const int* in_sizes, int n_in,
                              void* d_out, int out_size, void* d_ws, size_t ws_size,
                              hipStream_t stream) {
    const float* x     = (const float*)d_in[0];   // [2,2048,1024] fp32
    const float* gamma = (const float*)d_in[1];   // [1024] fp32
    const float* w_qkv = (const float*)d_in[2];   // [1024][3072] fp32
    const float* w_out = (const float*)d_in[3];   // [1024][1024] fp32
    float* out = (float*)d_out;                   // [4096][1024] fp32

    ushort_t* ws   = (ushort_t*)d_ws;
    ushort_t* xn   = ws;                                  // 4096*1024 (8MB, reused as attn)
    ushort_t* qkv  = xn + (size_t)4096 * 1024;            // 4096*3072 (24MB) Q|K|V
    ushort_t* vTb  = qkv + (size_t)4096 * 3072;           // 1024*4096 (8MB)  V^T
    ushort_t* wtq  = vTb + (size_t)1024 * 4096;           // 3072*1024 (6MB)
    ushort_t* wto  = wtq + (size_t)3072 * 1024;           // 1024*1024 (2MB)
    ushort_t* attn = xn;  // xn dead after QKV gemm; stream-serialized reuse

    rmsnorm_k<<<4096, 256, 0, stream>>>(x, gamma, xn);
    transpose_cvt2_k<<<1024, 256, 0, stream>>>(w_qkv, wtq, w_out, wto);
    // QKV: [4096 tok][3072 ch], 768 blocks = 3/CU
    gemm_tn<false><<<dim3(24, 32), 256, 0, stream>>>(xn, wtq, qkv, 4096, 3072, 1024);
    // V^T: [1024 ch][4096 tok] via bf16 transpose of V columns (L2-resident)
    transpose_v_k<<<dim3(64, 16), 256, 0, stream>>>(qkv, vTb);
    attn_k<<<512, 256, 0, stream>>>(qkv, vTb, attn);
    gemm_tn<true><<<dim3(8, 32), 256, 0, stream>>>(attn, wto, out, 4096, 1024, 1024);
}